// Round 11
// baseline (43.629 us; speedup 1.0000x reference)
//
#include <hip/hip_runtime.h>

// score[e] = dot(h[src[e]], h[dst[e]]), D=32.
// i8 global-scale table (3.2 MB -> fits per-XCD 4 MB L2), ONE edge pass.
//   k1: per-block absmax partials (shfl+LDS reduce, one store/block)
//   k2: quant_h — each block reduces the 1024 partials itself (4 KB, L2-hit;
//       removes r10's serialized absmax_final dispatch), block 0 publishes
//       gmax, then quantizes h -> i8 (exact max => no clamp)
//   k3: edge dot in int (4 lanes/edge x 8 B = 16 lines/instr), * (gmax/127)^2.
// Streaming accesses (h f32 reads, idx, out) are non-temporal so the i8 table
// stays L2-resident; table stores are normal (pre-warm).

constexpr int D_FEAT = 32;
constexpr int GRID   = 2048;
constexpr int BLOCK  = 256;
constexpr int RGRID  = 1024;   // absmax partial blocks

typedef float          f32x4 __attribute__((ext_vector_type(4)));
typedef unsigned int   u32x2 __attribute__((ext_vector_type(2)));

__global__ void __launch_bounds__(256) absmax_partial(
    const f32x4* __restrict__ h4, int n4, float* __restrict__ partials)
{
    float m = 0.f;
    int i = blockIdx.x * blockDim.x + threadIdx.x;
    const int stride = gridDim.x * blockDim.x;
    for (; i < n4; i += stride) {
        const f32x4 v = __builtin_nontemporal_load(&h4[i]);
        m = fmaxf(m, fmaxf(fmaxf(fabsf(v.x), fabsf(v.y)),
                           fmaxf(fabsf(v.z), fabsf(v.w))));
    }
    #pragma unroll
    for (int off = 32; off; off >>= 1) m = fmaxf(m, __shfl_xor(m, off));
    __shared__ float smax[4];
    if ((threadIdx.x & 63) == 0) smax[threadIdx.x >> 6] = m;
    __syncthreads();
    if (threadIdx.x == 0)
        partials[blockIdx.x] = fmaxf(fmaxf(smax[0], smax[1]),
                                     fmaxf(smax[2], smax[3]));
}

static __device__ __forceinline__ unsigned pack4(f32x4 v, float inv) {
    // |v| <= gmax exactly => |v*inv| <= 127, no clamp needed
    const int x0 = __float2int_rn(v.x * inv);
    const int x1 = __float2int_rn(v.y * inv);
    const int x2 = __float2int_rn(v.z * inv);
    const int x3 = __float2int_rn(v.w * inv);
    return (unsigned)(x0 & 0xff) | ((unsigned)(x1 & 0xff) << 8) |
           ((unsigned)(x2 & 0xff) << 16) | ((unsigned)(x3 & 0xff) << 24);
}

// Reduces partials in-block (no separate dispatch), publishes gmax (block 0),
// quantizes h -> i8.
__global__ void __launch_bounds__(256) quant_h(
    const f32x4* __restrict__ h4, u32x2* __restrict__ q8, int n8,
    const float* __restrict__ partials, int npart, float* __restrict__ gmax_out)
{
    float m = 0.f;
    for (int i = threadIdx.x; i < npart; i += BLOCK)
        m = fmaxf(m, partials[i]);
    #pragma unroll
    for (int off = 32; off; off >>= 1) m = fmaxf(m, __shfl_xor(m, off));
    __shared__ float smax[4];
    if ((threadIdx.x & 63) == 0) smax[threadIdx.x >> 6] = m;
    __syncthreads();
    const float gmax = fmaxf(fmaxf(smax[0], smax[1]), fmaxf(smax[2], smax[3]));
    if (blockIdx.x == 0 && threadIdx.x == 0) *gmax_out = gmax;

    const float inv = 127.f / gmax;
    int i = blockIdx.x * blockDim.x + threadIdx.x;
    const int stride = gridDim.x * blockDim.x;
    for (; i < n8; i += stride) {
        const f32x4 a = __builtin_nontemporal_load(&h4[2 * i]);
        const f32x4 b = __builtin_nontemporal_load(&h4[2 * i + 1]);
        u32x2 o;
        o.x = pack4(a, inv);
        o.y = pack4(b, inv);
        q8[i] = o;  // normal store: pre-warms L2 with the table
    }
}

static __device__ __forceinline__ int dot4(unsigned a, unsigned b) {
    int r;
    r  = ((int)(a << 24) >> 24) * ((int)(b << 24) >> 24);
    r += ((int)(a << 16) >> 24) * ((int)(b << 16) >> 24);
    r += ((int)(a <<  8) >> 24) * ((int)(b <<  8) >> 24);
    r += ((int) a        >> 24) * ((int) b        >> 24);
    return r;
}

__global__ void __launch_bounds__(256) edge_dot_i8(
    const unsigned char* __restrict__ q8,
    const int* __restrict__ src,
    const int* __restrict__ dst,
    float* __restrict__ out,
    int n_edges,
    const float* __restrict__ gmax)
{
    const float sc = *gmax / 127.f;
    const float s2 = sc * sc;

    const int g = threadIdx.x & 3;  // 4 lanes/edge, 8 B each (32-B row)
    const int group = (blockIdx.x * blockDim.x + threadIdx.x) >> 2;
    const int n_groups = (GRID * BLOCK) >> 2;

    for (int e = group; e < n_edges; e += n_groups) {
        const int s = __builtin_nontemporal_load(&src[e]);
        const int d = __builtin_nontemporal_load(&dst[e]);
        const u32x2 a = *reinterpret_cast<const u32x2*>(
            q8 + (size_t)s * D_FEAT + g * 8);
        const u32x2 b = *reinterpret_cast<const u32x2*>(
            q8 + (size_t)d * D_FEAT + g * 8);
        int acc = dot4(a.x, b.x) + dot4(a.y, b.y);
        acc += __shfl_xor(acc, 1);
        acc += __shfl_xor(acc, 2);
        if (g == 0) __builtin_nontemporal_store((float)acc * s2, &out[e]);
    }
}

// f32 fallback (if ws too small)
__global__ void __launch_bounds__(256) edge_dot_f32(
    const float* __restrict__ h,
    const int* __restrict__ src,
    const int* __restrict__ dst,
    float* __restrict__ out,
    int n_edges)
{
    const int g = threadIdx.x & 7;
    const int group = (blockIdx.x * blockDim.x + threadIdx.x) >> 3;
    const int n_groups = (gridDim.x * blockDim.x) >> 3;
    for (int e = group; e < n_edges; e += n_groups) {
        const int s = src[e];
        const int d = dst[e];
        const f32x4 a = reinterpret_cast<const f32x4*>(h + (size_t)s * D_FEAT)[g];
        const f32x4 b = reinterpret_cast<const f32x4*>(h + (size_t)d * D_FEAT)[g];
        float acc = a.x * b.x + a.y * b.y + a.z * b.z + a.w * b.w;
        acc += __shfl_xor(acc, 1);
        acc += __shfl_xor(acc, 2);
        acc += __shfl_xor(acc, 4);
        if (g == 0) out[e] = acc;
    }
}

extern "C" void kernel_launch(void* const* d_in, const int* in_sizes, int n_in,
                              void* d_out, int out_size, void* d_ws, size_t ws_size,
                              hipStream_t stream) {
    const float* h   = (const float*)d_in[0];
    const int*   src = (const int*)d_in[1];
    const int*   dst = (const int*)d_in[2];
    float*       out = (float*)d_out;
    const int n_h     = in_sizes[0];           // N_NODES * D_FEAT
    const int n_edges = in_sizes[1];

    // ws layout: [0,4): gmax; [256, 256+4K): partials; [8192, 8192+n_h): i8
    const size_t need = 8192 + (size_t)n_h;
    if (ws_size >= need && (n_h % 8) == 0) {
        float* gmax     = (float*)d_ws;
        float* partials = (float*)((char*)d_ws + 256);
        unsigned char* q8 = (unsigned char*)d_ws + 8192;
        absmax_partial<<<RGRID, BLOCK, 0, stream>>>(
            (const f32x4*)h, n_h / 4, partials);
        quant_h<<<GRID, BLOCK, 0, stream>>>(
            (const f32x4*)h, (u32x2*)q8, n_h / 8, partials, RGRID, gmax);
        edge_dot_i8<<<GRID, BLOCK, 0, stream>>>(
            q8, src, dst, out, n_edges, gmax);
    } else {
        edge_dot_f32<<<2048, 256, 0, stream>>>(h, src, dst, out, n_edges);
    }
}

// Round 12
// 35.855 us; speedup vs baseline: 1.2168x; 1.2168x over previous
//
#include <hip/hip_runtime.h>

// score[e] = dot(h[src[e]], h[dst[e]]), D=32.
// i8 global-scale table (3.2 MB -> fits per-XCD 4 MB L2), ONE edge pass.
//   k1: per-block absmax partials (shfl+LDS reduce, one store/block)
//   k2: quant_h — each block reduces the 1024 partials itself (4 KB, L2-hit;
//       removes the serialized absmax_final dispatch), block 0 publishes
//       gmax, then quantizes h -> i8 (exact max => no clamp)
//   k3: edge dot in int (4 lanes/edge x 8 B = 16 lines/instr), * (gmax/127)^2.
// NO nontemporal hints anywhere: r6 (+2.6 us) and r11 (+6 us) both showed
// __builtin_nontemporal_* REGRESSES on gfx950 streams.

constexpr int D_FEAT = 32;
constexpr int GRID   = 2048;
constexpr int BLOCK  = 256;
constexpr int RGRID  = 1024;   // absmax partial blocks

typedef float          f32x4 __attribute__((ext_vector_type(4)));
typedef unsigned int   u32x2 __attribute__((ext_vector_type(2)));

__global__ void __launch_bounds__(256) absmax_partial(
    const f32x4* __restrict__ h4, int n4, float* __restrict__ partials)
{
    float m = 0.f;
    int i = blockIdx.x * blockDim.x + threadIdx.x;
    const int stride = gridDim.x * blockDim.x;
    for (; i < n4; i += stride) {
        const f32x4 v = h4[i];
        m = fmaxf(m, fmaxf(fmaxf(fabsf(v.x), fabsf(v.y)),
                           fmaxf(fabsf(v.z), fabsf(v.w))));
    }
    #pragma unroll
    for (int off = 32; off; off >>= 1) m = fmaxf(m, __shfl_xor(m, off));
    __shared__ float smax[4];
    if ((threadIdx.x & 63) == 0) smax[threadIdx.x >> 6] = m;
    __syncthreads();
    if (threadIdx.x == 0)
        partials[blockIdx.x] = fmaxf(fmaxf(smax[0], smax[1]),
                                     fmaxf(smax[2], smax[3]));
}

static __device__ __forceinline__ unsigned pack4(f32x4 v, float inv) {
    // |v| <= gmax exactly => |v*inv| <= 127, no clamp needed
    const int x0 = __float2int_rn(v.x * inv);
    const int x1 = __float2int_rn(v.y * inv);
    const int x2 = __float2int_rn(v.z * inv);
    const int x3 = __float2int_rn(v.w * inv);
    return (unsigned)(x0 & 0xff) | ((unsigned)(x1 & 0xff) << 8) |
           ((unsigned)(x2 & 0xff) << 16) | ((unsigned)(x3 & 0xff) << 24);
}

// Reduces partials in-block (no separate dispatch), publishes gmax (block 0),
// quantizes h -> i8.
__global__ void __launch_bounds__(256) quant_h(
    const f32x4* __restrict__ h4, u32x2* __restrict__ q8, int n8,
    const float* __restrict__ partials, int npart, float* __restrict__ gmax_out)
{
    float m = 0.f;
    for (int i = threadIdx.x; i < npart; i += BLOCK)
        m = fmaxf(m, partials[i]);
    #pragma unroll
    for (int off = 32; off; off >>= 1) m = fmaxf(m, __shfl_xor(m, off));
    __shared__ float smax[4];
    if ((threadIdx.x & 63) == 0) smax[threadIdx.x >> 6] = m;
    __syncthreads();
    const float gmax = fmaxf(fmaxf(smax[0], smax[1]), fmaxf(smax[2], smax[3]));
    if (blockIdx.x == 0 && threadIdx.x == 0) *gmax_out = gmax;

    const float inv = 127.f / gmax;
    int i = blockIdx.x * blockDim.x + threadIdx.x;
    const int stride = gridDim.x * blockDim.x;
    for (; i < n8; i += stride) {
        const f32x4 a = h4[2 * i];
        const f32x4 b = h4[2 * i + 1];
        u32x2 o;
        o.x = pack4(a, inv);
        o.y = pack4(b, inv);
        q8[i] = o;  // 8-B coalesced store; pre-warms L2 with the table
    }
}

static __device__ __forceinline__ int dot4(unsigned a, unsigned b) {
    int r;
    r  = ((int)(a << 24) >> 24) * ((int)(b << 24) >> 24);
    r += ((int)(a << 16) >> 24) * ((int)(b << 16) >> 24);
    r += ((int)(a <<  8) >> 24) * ((int)(b <<  8) >> 24);
    r += ((int) a        >> 24) * ((int) b        >> 24);
    return r;
}

__global__ void __launch_bounds__(256) edge_dot_i8(
    const unsigned char* __restrict__ q8,
    const int* __restrict__ src,
    const int* __restrict__ dst,
    float* __restrict__ out,
    int n_edges,
    const float* __restrict__ gmax)
{
    const float sc = *gmax / 127.f;
    const float s2 = sc * sc;

    const int g = threadIdx.x & 3;  // 4 lanes/edge, 8 B each (32-B row)
    const int group = (blockIdx.x * blockDim.x + threadIdx.x) >> 2;
    const int n_groups = (GRID * BLOCK) >> 2;

    for (int e = group; e < n_edges; e += n_groups) {
        const int s = src[e];
        const int d = dst[e];
        const u32x2 a = *reinterpret_cast<const u32x2*>(
            q8 + (size_t)s * D_FEAT + g * 8);
        const u32x2 b = *reinterpret_cast<const u32x2*>(
            q8 + (size_t)d * D_FEAT + g * 8);
        int acc = dot4(a.x, b.x) + dot4(a.y, b.y);
        acc += __shfl_xor(acc, 1);
        acc += __shfl_xor(acc, 2);
        if (g == 0) out[e] = (float)acc * s2;
    }
}

// f32 fallback (if ws too small)
__global__ void __launch_bounds__(256) edge_dot_f32(
    const float* __restrict__ h,
    const int* __restrict__ src,
    const int* __restrict__ dst,
    float* __restrict__ out,
    int n_edges)
{
    const int g = threadIdx.x & 7;
    const int group = (blockIdx.x * blockDim.x + threadIdx.x) >> 3;
    const int n_groups = (gridDim.x * blockDim.x) >> 3;
    for (int e = group; e < n_edges; e += n_groups) {
        const int s = src[e];
        const int d = dst[e];
        const f32x4 a = reinterpret_cast<const f32x4*>(h + (size_t)s * D_FEAT)[g];
        const f32x4 b = reinterpret_cast<const f32x4*>(h + (size_t)d * D_FEAT)[g];
        float acc = a.x * b.x + a.y * b.y + a.z * b.z + a.w * b.w;
        acc += __shfl_xor(acc, 1);
        acc += __shfl_xor(acc, 2);
        acc += __shfl_xor(acc, 4);
        if (g == 0) out[e] = acc;
    }
}

extern "C" void kernel_launch(void* const* d_in, const int* in_sizes, int n_in,
                              void* d_out, int out_size, void* d_ws, size_t ws_size,
                              hipStream_t stream) {
    const float* h   = (const float*)d_in[0];
    const int*   src = (const int*)d_in[1];
    const int*   dst = (const int*)d_in[2];
    float*       out = (float*)d_out;
    const int n_h     = in_sizes[0];           // N_NODES * D_FEAT
    const int n_edges = in_sizes[1];

    // ws layout: [0,4): gmax; [256, 256+4K): partials; [8192, 8192+n_h): i8
    const size_t need = 8192 + (size_t)n_h;
    if (ws_size >= need && (n_h % 8) == 0) {
        float* gmax     = (float*)d_ws;
        float* partials = (float*)((char*)d_ws + 256);
        unsigned char* q8 = (unsigned char*)d_ws + 8192;
        absmax_partial<<<RGRID, BLOCK, 0, stream>>>(
            (const f32x4*)h, n_h / 4, partials);
        quant_h<<<GRID, BLOCK, 0, stream>>>(
            (const f32x4*)h, (u32x2*)q8, n_h / 8, partials, RGRID, gmax);
        edge_dot_i8<<<GRID, BLOCK, 0, stream>>>(
            q8, src, dst, out, n_edges, gmax);
    } else {
        edge_dot_f32<<<2048, 256, 0, stream>>>(h, src, dst, out, n_edges);
    }
}

// Round 13
// 35.719 us; speedup vs baseline: 1.2214x; 1.0038x over previous
//
#include <hip/hip_runtime.h>

// score[e] = dot(h[src[e]], h[dst[e]]), D=32.
// i8 global-scale table (3.2 MB -> fits per-XCD 4 MB L2), ONE edge pass.
//   k1: per-block absmax partials (shfl+LDS reduce, one store/block)
//   k2: quant_h — in-block reduce of the 1024 partials (4 KB, L2-hit),
//       block 0 publishes gmax, then quantize h -> i8 (exact max => no clamp)
//   k3: edge dot in int (4 lanes/edge x 8 B), * (gmax/127)^2.
// NEW vs r12: row-gathers use inline-asm buffer_load_dwordx2 with SC0
// (L1-bypass, serviced by L2). Rationale: 3.2 MB table in 32 KiB L1 = ~1%
// hit rate; per-miss L1/MSHR processing (~4 cy) was the edge-kernel wall
// (observed ~24 us vs ~6 us TA-rate model). NO nontemporal hints anywhere
// (r6/r11: nt regresses streams on gfx950).

constexpr int D_FEAT = 32;
constexpr int GRID   = 2048;
constexpr int BLOCK  = 256;
constexpr int RGRID  = 1024;   // absmax partial blocks

typedef float          f32x4 __attribute__((ext_vector_type(4)));
typedef unsigned int   u32x2 __attribute__((ext_vector_type(2)));
typedef unsigned int   u32x4 __attribute__((ext_vector_type(4)));

__global__ void __launch_bounds__(256) absmax_partial(
    const f32x4* __restrict__ h4, int n4, float* __restrict__ partials)
{
    float m = 0.f;
    int i = blockIdx.x * blockDim.x + threadIdx.x;
    const int stride = gridDim.x * blockDim.x;
    for (; i < n4; i += stride) {
        const f32x4 v = h4[i];
        m = fmaxf(m, fmaxf(fmaxf(fabsf(v.x), fabsf(v.y)),
                           fmaxf(fabsf(v.z), fabsf(v.w))));
    }
    #pragma unroll
    for (int off = 32; off; off >>= 1) m = fmaxf(m, __shfl_xor(m, off));
    __shared__ float smax[4];
    if ((threadIdx.x & 63) == 0) smax[threadIdx.x >> 6] = m;
    __syncthreads();
    if (threadIdx.x == 0)
        partials[blockIdx.x] = fmaxf(fmaxf(smax[0], smax[1]),
                                     fmaxf(smax[2], smax[3]));
}

static __device__ __forceinline__ unsigned pack4(f32x4 v, float inv) {
    // |v| <= gmax exactly => |v*inv| <= 127, no clamp needed
    const int x0 = __float2int_rn(v.x * inv);
    const int x1 = __float2int_rn(v.y * inv);
    const int x2 = __float2int_rn(v.z * inv);
    const int x3 = __float2int_rn(v.w * inv);
    return (unsigned)(x0 & 0xff) | ((unsigned)(x1 & 0xff) << 8) |
           ((unsigned)(x2 & 0xff) << 16) | ((unsigned)(x3 & 0xff) << 24);
}

// Reduces partials in-block (no separate dispatch), publishes gmax (block 0),
// quantizes h -> i8.
__global__ void __launch_bounds__(256) quant_h(
    const f32x4* __restrict__ h4, u32x2* __restrict__ q8, int n8,
    const float* __restrict__ partials, int npart, float* __restrict__ gmax_out)
{
    float m = 0.f;
    for (int i = threadIdx.x; i < npart; i += BLOCK)
        m = fmaxf(m, partials[i]);
    #pragma unroll
    for (int off = 32; off; off >>= 1) m = fmaxf(m, __shfl_xor(m, off));
    __shared__ float smax[4];
    if ((threadIdx.x & 63) == 0) smax[threadIdx.x >> 6] = m;
    __syncthreads();
    const float gmax = fmaxf(fmaxf(smax[0], smax[1]), fmaxf(smax[2], smax[3]));
    if (blockIdx.x == 0 && threadIdx.x == 0) *gmax_out = gmax;

    const float inv = 127.f / gmax;
    int i = blockIdx.x * blockDim.x + threadIdx.x;
    const int stride = gridDim.x * blockDim.x;
    for (; i < n8; i += stride) {
        const f32x4 a = h4[2 * i];
        const f32x4 b = h4[2 * i + 1];
        u32x2 o;
        o.x = pack4(a, inv);
        o.y = pack4(b, inv);
        q8[i] = o;  // 8-B coalesced store; pre-warms L2 with the table
    }
}

static __device__ __forceinline__ int dot4(unsigned a, unsigned b) {
    int r;
    r  = ((int)(a << 24) >> 24) * ((int)(b << 24) >> 24);
    r += ((int)(a << 16) >> 24) * ((int)(b << 16) >> 24);
    r += ((int)(a <<  8) >> 24) * ((int)(b <<  8) >> 24);
    r += ((int) a        >> 24) * ((int) b        >> 24);
    return r;
}

__global__ void __launch_bounds__(256) edge_dot_i8(
    const unsigned char* __restrict__ q8,
    const int* __restrict__ src,
    const int* __restrict__ dst,
    float* __restrict__ out,
    int n_edges,
    int n_nodes,
    const float* __restrict__ gmax)
{
    const float sc = *gmax / 127.f;
    const float s2 = sc * sc;

    // SRSRC for the i8 table: base, stride=0, num_records = table bytes
    u32x4 srsrc;
    {
        const unsigned long long a = (unsigned long long)q8;
        srsrc.x = (unsigned)a;
        srsrc.y = (unsigned)(a >> 32);
        srsrc.z = (unsigned)n_nodes * (unsigned)D_FEAT;  // bytes (stride==0)
        srsrc.w = 0x00020000u;
    }

    const int g = threadIdx.x & 3;  // 4 lanes/edge, 8 B each (32-B row)
    const int group = (blockIdx.x * blockDim.x + threadIdx.x) >> 2;
    const int n_groups = (GRID * BLOCK) >> 2;

    for (int e = group; e < n_edges; e += n_groups) {
        const int s = src[e];
        const int d = dst[e];
        const unsigned voff_s = (unsigned)s * (unsigned)D_FEAT + (unsigned)g * 8u;
        const unsigned voff_d = (unsigned)d * (unsigned)D_FEAT + (unsigned)g * 8u;
        u32x2 a, b;
        // SC0 = L1-bypass (device-coherent read, serviced by L2). Two loads
        // share one waitcnt to keep both misses in flight.
        asm volatile(
            "buffer_load_dwordx2 %0, %2, %4, 0 offen sc0\n\t"
            "buffer_load_dwordx2 %1, %3, %4, 0 offen sc0\n\t"
            "s_waitcnt vmcnt(0)"
            : "=&v"(a), "=&v"(b)
            : "v"(voff_s), "v"(voff_d), "s"(srsrc)
            : "memory");
        int acc = dot4(a.x, b.x) + dot4(a.y, b.y);
        acc += __shfl_xor(acc, 1);
        acc += __shfl_xor(acc, 2);
        if (g == 0) out[e] = (float)acc * s2;
    }
}

// f32 fallback (if ws too small)
__global__ void __launch_bounds__(256) edge_dot_f32(
    const float* __restrict__ h,
    const int* __restrict__ src,
    const int* __restrict__ dst,
    float* __restrict__ out,
    int n_edges)
{
    const int g = threadIdx.x & 7;
    const int group = (blockIdx.x * blockDim.x + threadIdx.x) >> 3;
    const int n_groups = (gridDim.x * blockDim.x) >> 3;
    for (int e = group; e < n_edges; e += n_groups) {
        const int s = src[e];
        const int d = dst[e];
        const f32x4 a = reinterpret_cast<const f32x4*>(h + (size_t)s * D_FEAT)[g];
        const f32x4 b = reinterpret_cast<const f32x4*>(h + (size_t)d * D_FEAT)[g];
        float acc = a.x * b.x + a.y * b.y + a.z * b.z + a.w * b.w;
        acc += __shfl_xor(acc, 1);
        acc += __shfl_xor(acc, 2);
        acc += __shfl_xor(acc, 4);
        if (g == 0) out[e] = acc;
    }
}

extern "C" void kernel_launch(void* const* d_in, const int* in_sizes, int n_in,
                              void* d_out, int out_size, void* d_ws, size_t ws_size,
                              hipStream_t stream) {
    const float* h   = (const float*)d_in[0];
    const int*   src = (const int*)d_in[1];
    const int*   dst = (const int*)d_in[2];
    float*       out = (float*)d_out;
    const int n_h     = in_sizes[0];           // N_NODES * D_FEAT
    const int n_edges = in_sizes[1];
    const int n_nodes = n_h / D_FEAT;

    // ws layout: [0,4): gmax; [256, 256+4K): partials; [8192, 8192+n_h): i8
    const size_t need = 8192 + (size_t)n_h;
    if (ws_size >= need && (n_h % 8) == 0) {
        float* gmax     = (float*)d_ws;
        float* partials = (float*)((char*)d_ws + 256);
        unsigned char* q8 = (unsigned char*)d_ws + 8192;
        absmax_partial<<<RGRID, BLOCK, 0, stream>>>(
            (const f32x4*)h, n_h / 4, partials);
        quant_h<<<GRID, BLOCK, 0, stream>>>(
            (const f32x4*)h, (u32x2*)q8, n_h / 8, partials, RGRID, gmax);
        edge_dot_i8<<<GRID, BLOCK, 0, stream>>>(
            q8, src, dst, out, n_edges, n_nodes, gmax);
    } else {
        edge_dot_f32<<<2048, 256, 0, stream>>>(h, src, dst, out, n_edges);
    }
}